// Round 3
// baseline (177.948 us; speedup 1.0000x reference)
//
#include <hip/hip_runtime.h>

#define EPS 1e-7f

// Native clang vector type: accepted by __builtin_nontemporal_store
// (HIP's float4 class is not).
typedef float floatx4 __attribute__((ext_vector_type(4)));

// 8 consecutive samples per thread: all global accesses float4-aligned.
// d rows: 8 x 6 floats = 12 float4; e rows: 8 x 5 floats = 10 float4.
// Deep load pipeline per wave (22 loads in flight) + nontemporal stores
// so the 84 MB write stream doesn't evict L3-warm inputs.
__global__ __launch_bounds__(256) void attn_e_kernel(
    const float* __restrict__ dp, const float* __restrict__ ep,
    const float* __restrict__ Wp, const float* __restrict__ bp,
    float* __restrict__ out, int n8) // n8 = N/8
{
    int i = blockIdx.x * blockDim.x + threadIdx.x;
    if (i >= n8) return;

    float W = Wp[0];
    float bb[5];
    #pragma unroll
    for (int j = 0; j < 5; ++j) bb[j] = bp[j];

    const floatx4* d4 = (const floatx4*)dp;
    const floatx4* e4 = (const floatx4*)ep;

    floatx4 dv[12], ev[10];
    #pragma unroll
    for (int k = 0; k < 12; ++k) dv[k] = d4[(size_t)i * 12 + k];
    #pragma unroll
    for (int k = 0; k < 10; ++k) ev[k] = e4[(size_t)i * 10 + k];

    const float* df = (const float*)dv; // 48 floats = 8 rows x 6
    const float* ef = (const float*)ev; // 40 floats = 8 rows x 5
    float of[40];

    #pragma unroll
    for (int r = 0; r < 8; ++r) {
        float s = 0.f;
        #pragma unroll
        for (int k = 0; k < 6; ++k) s += df[r * 6 + k];
        float sw = s * W;

        float a[5];
        float asum = 0.f;
        #pragma unroll
        for (int j = 0; j < 5; ++j) {
            float x = sw * ef[r * 5 + j] + bb[j];
            // tanh(x) = 1 - 2/(exp(2x)+1); saturates correctly at +/-inf.
            float t = 1.f - 2.f / (__expf(2.f * x) + 1.f);
            float av = __expf(t);
            a[j] = av;
            asum += av;
        }
        float inv = 1.f / (asum + EPS);
        #pragma unroll
        for (int j = 0; j < 5; ++j) of[r * 5 + j] = ef[r * 5 + j] * (a[j] * inv);
    }

    floatx4* o4 = (floatx4*)out;
    const floatx4* ofv = (const floatx4*)of;
    #pragma unroll
    for (int k = 0; k < 10; ++k)
        __builtin_nontemporal_store(ofv[k], &o4[(size_t)i * 10 + k]);
}

extern "C" void kernel_launch(void* const* d_in, const int* in_sizes, int n_in,
                              void* d_out, int out_size, void* d_ws, size_t ws_size,
                              hipStream_t stream) {
    const float* dp = (const float*)d_in[0]; // (N,6)
    const float* ep = (const float*)d_in[1]; // (N,5)
    const float* Wp = (const float*)d_in[2]; // (1,)
    const float* bp = (const float*)d_in[3]; // (5,)
    float* out = (float*)d_out;              // (N,5)

    int N = in_sizes[1] / 5; // e is N*5 elements
    int n8 = N / 8;          // N = 4194304 divisible by 8
    int threads = 256;
    int blocks = (n8 + threads - 1) / threads;
    attn_e_kernel<<<blocks, threads, 0, stream>>>(dp, ep, Wp, bp, out, n8);
}

// Round 4
// 104.019 us; speedup vs baseline: 1.7107x; 1.7107x over previous
//
#include <hip/hip_runtime.h>

#define EPS 1e-7f

// Native clang vector type: accepted by __builtin_nontemporal_store and
// component-indexable with compile-time constants (SROA-friendly).
typedef float floatx4 __attribute__((ext_vector_type(4)));

// 4 consecutive samples per thread: all global accesses float4-aligned.
// d rows: 4 x 6 floats = 6 float4; e rows: 4 x 5 floats = 5 float4.
// CRITICAL: no reinterpret-casts of local arrays (address-taking defeats
// SROA -> scratch spill -> 2-3x HBM traffic, seen in R3). All element
// accesses use dv[f>>2][f&3] with f a constant after full unroll.
__global__ __launch_bounds__(256) void attn_e_kernel(
    const float* __restrict__ dp, const float* __restrict__ ep,
    const float* __restrict__ Wp, const float* __restrict__ bp,
    float* __restrict__ out, int n4) // n4 = N/4
{
    int i = blockIdx.x * blockDim.x + threadIdx.x;
    if (i >= n4) return;

    float W = Wp[0];
    float bb[5];
    #pragma unroll
    for (int j = 0; j < 5; ++j) bb[j] = bp[j];

    const floatx4* d4 = (const floatx4*)dp;
    const floatx4* e4 = (const floatx4*)ep;

    floatx4 dv[6], ev[5], ov[5];
    #pragma unroll
    for (int k = 0; k < 6; ++k) dv[k] = d4[(size_t)i * 6 + k];
    #pragma unroll
    for (int k = 0; k < 5; ++k) ev[k] = e4[(size_t)i * 5 + k];

    #pragma unroll
    for (int r = 0; r < 4; ++r) {
        float s = 0.f;
        #pragma unroll
        for (int k = 0; k < 6; ++k) {
            int f = r * 6 + k;            // constant after unroll
            s += dv[f >> 2][f & 3];
        }
        float sw = s * W;

        float a[5];
        float asum = 0.f;
        #pragma unroll
        for (int j = 0; j < 5; ++j) {
            int f = r * 5 + j;
            float x = sw * ev[f >> 2][f & 3] + bb[j];
            // tanh(x) = 1 - 2/(exp(2x)+1); saturates correctly at +/-inf.
            float t = 1.f - 2.f / (__expf(2.f * x) + 1.f);
            float av = __expf(t);
            a[j] = av;
            asum += av;
        }
        float inv = 1.f / (asum + EPS);
        #pragma unroll
        for (int j = 0; j < 5; ++j) {
            int f = r * 5 + j;
            ov[f >> 2][f & 3] = ev[f >> 2][f & 3] * (a[j] * inv);
        }
    }

    floatx4* o4 = (floatx4*)out;
    #pragma unroll
    for (int k = 0; k < 5; ++k)
        __builtin_nontemporal_store(ov[k], &o4[(size_t)i * 5 + k]);
}

extern "C" void kernel_launch(void* const* d_in, const int* in_sizes, int n_in,
                              void* d_out, int out_size, void* d_ws, size_t ws_size,
                              hipStream_t stream) {
    const float* dp = (const float*)d_in[0]; // (N,6)
    const float* ep = (const float*)d_in[1]; // (N,5)
    const float* Wp = (const float*)d_in[2]; // (1,)
    const float* bp = (const float*)d_in[3]; // (5,)
    float* out = (float*)d_out;              // (N,5)

    int N = in_sizes[1] / 5; // e is N*5 elements
    int n4 = N / 4;          // N = 4194304 divisible by 4
    int threads = 256;
    int blocks = (n4 + threads - 1) / threads;
    attn_e_kernel<<<blocks, threads, 0, stream>>>(dp, ep, Wp, bp, out, n4);
}